// Round 8
// baseline (1502.286 us; speedup 1.0000x reference)
//
#include <hip/hip_runtime.h>
#include <hip/hip_bf16.h>

typedef unsigned short u16;
typedef unsigned int u32;
typedef __attribute__((ext_vector_type(8))) short bf16x8;
typedef __attribute__((ext_vector_type(4))) float f32x4;

#define DEV static __device__ __forceinline__

// fp32 -> bf16, round-to-nearest-even
DEV u16 f2b(float f) {
  union { float f; u32 u; } v; v.f = f;
  return (u16)((v.u + 0x7fffu + ((v.u >> 16) & 1u)) >> 16);
}

// async global->LDS, 16B per lane. LDS dest linear in lane order.
DEV void gload16(const void* g, void* l) {
  __builtin_amdgcn_global_load_lds(
      (const __attribute__((address_space(1))) u32*)g,
      (__attribute__((address_space(3))) u32*)l, 16, 0, 0);
}

// ---------------------------------------------------------------- converts
__global__ __launch_bounds__(256) void cvt_bf16(const float* __restrict__ s,
                                                u16* __restrict__ d) {
  const long i = ((long)blockIdx.x * 256 + threadIdx.x) * 4;
  const float4 v = *(const float4*)&s[i];
  ushort4 o;
  o.x = f2b(v.x); o.y = f2b(v.y); o.z = f2b(v.z); o.w = f2b(v.w);
  *(ushort4*)&d[i] = o;
}

// src [bz][R][C] fp32 -> dst: elem [c][r] at dst + bz*dStride + c*ldd + r
__global__ __launch_bounds__(256) void tpose_bf16(const float* __restrict__ src,
                                                  u16* __restrict__ dst, int R,
                                                  int C, long sStride,
                                                  long dStride, long ldd) {
  __shared__ float tl[32][33];
  const float* s = src + (long)blockIdx.z * sStride;
  u16* d = dst + (long)blockIdx.z * dStride;
  const int c0 = blockIdx.x * 32, r0 = blockIdx.y * 32;
  const int tx = threadIdx.x, ty = threadIdx.y;  // (32,8)
  const int tid = ty * 32 + tx;
#pragma unroll
  for (int k = 0; k < 4; k++)
    tl[ty + k * 8][tx] = s[(long)(r0 + ty + k * 8) * C + c0 + tx];
  __syncthreads();
  // vectorized write: thread -> out col c = tid>>3, rows (tid&7)*4 .. +3
  const int oc = tid >> 3, orb = (tid & 7) * 4;
  ushort4 o;
  o.x = f2b(tl[orb + 0][oc]);
  o.y = f2b(tl[orb + 1][oc]);
  o.z = f2b(tl[orb + 2][oc]);
  o.w = f2b(tl[orb + 3][oc]);
  *(ushort4*)&d[(long)(c0 + oc) * ldd + r0 + orb] = o;
}

// ---------------------------------------------------------------- GEMM
// C[row][col] = sum_k A[row][k] * Bt[col][k]   (A row-major, B^T row-major)
// 128x128 tile, BK=32, 4 waves (2x2), 4x4 mfma_f32_16x16x32_bf16 per K-step.
// TRIPLE-buffered LDS pipeline, counted vmcnt (T4): at step t, issue stage of
// tile t+2, compute tile t, then s_waitcnt vmcnt(4) (keeps t+2's 4 loads in
// flight, guarantees t+1 landed) + raw s_barrier. sched_barrier(0) AFTER the
// s_barrier pins next-iter ds_reads behind it (raw s_barrier has no fence
// semantics; rule 18 — hipcc hoists LDS reads across inline-asm waits).
enum { EQKV, EPROJ, EFF1, EFF2, EFF2I };

template <int EPI>
__global__ __launch_bounds__(256, 3) void gemm_bt(
    const u16* __restrict__ A, const u16* __restrict__ Bt, int K, long lda,
    long ldb, const float* __restrict__ c0, const float* __restrict__ c1,
    const float* __restrict__ c2, const float* __restrict__ aux,
    float* __restrict__ fout, u16* __restrict__ o0, u16* __restrict__ o1,
    u16* __restrict__ o2, int ebase, long ldc) {
  __shared__ u16 As[12288], Bs[12288];  // 3 bufs x (128 rows x 32 k) each
  long zc = 0;
  if constexpr (EPI == EFF2 || EPI == EFF2I) {  // K-split over grid.z
    const long z = blockIdx.z;
    A += z * (long)K;
    Bt += z * (long)K;
    fout += z * 4194304;  // per-z fp32 partial [4096][1024]
  }
  if constexpr (EPI == EFF1) {  // expert-batch over grid.z
    Bt += (long)blockIdx.z * 4194304;
    zc = (long)blockIdx.z * 4096;
  }
  const int tid = threadIdx.x;
  const int m0 = blockIdx.y * 128, n0 = blockIdx.x * 128;
  const int w = tid >> 6, l = tid & 63;
  const int wm = (w >> 1) * 64, wn = (w & 1) * 64;
  const int lr = l & 15, lh = l >> 4;
  f32x4 acc[4][4] = {};
  const u16* AgB = A + (long)(m0 + (tid >> 2)) * lda + (tid & 3) * 8;
  const u16* BgB = Bt + (long)(n0 + (tid >> 2)) * ldb + (tid & 3) * 8;
  const long rsA = 64 * lda, rsB = 64 * ldb;
  u16* asd = As + tid * 8;
  u16* bsd = Bs + tid * 8;
  const int nt = K >> 5;
  // prologue: stage tiles 0 (buf0) and 1 (buf1); wait tile 0 (leave 4 out)
  gload16(AgB, asd);             gload16(AgB + rsA, asd + 2048);
  gload16(BgB, bsd);             gload16(BgB + rsB, bsd + 2048);
  gload16(AgB + 32, asd + 4096); gload16(AgB + rsA + 32, asd + 6144);
  gload16(BgB + 32, bsd + 4096); gload16(BgB + rsB + 32, bsd + 6144);
  asm volatile("s_waitcnt vmcnt(4)" ::: "memory");
  __builtin_amdgcn_sched_barrier(0);
  __builtin_amdgcn_s_barrier();
  __builtin_amdgcn_sched_barrier(0);
  int oc = 0, on = 4096, ot = 8192;  // u16 offsets of bufs t, t+1, t+2
  for (int t = 0; t < nt; ++t) {
    // issue stage of tile t+2 into buf ot (clamped tail: never read)
    const int ks = (t + 2 < nt ? t + 2 : nt - 1) * 32;
    gload16(AgB + ks, asd + ot);
    gload16(AgB + rsA + ks, asd + ot + 2048);
    gload16(BgB + ks, bsd + ot);
    gload16(BgB + rsB + ks, bsd + ot + 2048);
    // compute tile t from buf oc
    bf16x8 af[4], bfr[4];
#pragma unroll
    for (int i = 0; i < 4; i++)
      af[i] = *(const bf16x8*)&As[oc + (wm + i * 16 + lr) * 32 + lh * 8];
#pragma unroll
    for (int j = 0; j < 4; j++)
      bfr[j] = *(const bf16x8*)&Bs[oc + (wn + j * 16 + lr) * 32 + lh * 8];
    __builtin_amdgcn_s_setprio(1);
#pragma unroll
    for (int i = 0; i < 4; i++)
#pragma unroll
      for (int j = 0; j < 4; j++)
        acc[i][j] = __builtin_amdgcn_mfma_f32_16x16x32_bf16(af[i], bfr[j],
                                                            acc[i][j], 0, 0, 0);
    __builtin_amdgcn_s_setprio(0);
    // counted wait: t+1 landed, t+2's 4 loads stay in flight. Raw barrier.
    asm volatile("s_waitcnt vmcnt(4)" ::: "memory");
    __builtin_amdgcn_sched_barrier(0);
    __builtin_amdgcn_s_barrier();
    __builtin_amdgcn_sched_barrier(0);  // pin next-iter ds_reads behind barrier
    const int tmp = oc; oc = on; on = ot; ot = tmp;
  }
  asm volatile("s_waitcnt vmcnt(0)" ::: "memory");  // drain before retire
  // epilogue: elem (i,j,r) -> row = m0+wm+i*16+lh*4+r, col = n0+wn+j*16+lr
#pragma unroll
  for (int j = 0; j < 4; j++) {
    const int col = n0 + wn + j * 16 + lr;
#pragma unroll
    for (int i = 0; i < 4; i++)
#pragma unroll
      for (int r = 0; r < 4; r++) {
        const int row = m0 + wm + i * 16 + lh * 4 + r;
        float v = acc[i][j][r];
        if constexpr (EPI == EQKV) {
          const int which = col >> 10, hd = col & 1023;
          const float vb =
              v + ((which == 0) ? c0 : (which == 1) ? c1 : c2)[hd];
          const int b = row >> 10, s = row & 1023;
          const int h = hd >> 6, d = hd & 63;
          const long bh = b * 16 + h;
          if (which == 0)
            o0[(bh * 1024 + s) * 64 + d] = f2b(vb * 0.125f);  // q pre-scaled
          else if (which == 1)
            o1[(bh * 1024 + s) * 64 + d] = f2b(vb);           // k
          else
            o2[bh * 65536 + (long)d * 1024 + s] = f2b(vb);    // v transposed
        } else if constexpr (EPI == EPROJ) {
          const long idx = (long)row * 1024 + col;
          fout[idx] = v + c0[col] + aux[idx];  // + bp + x residual
        } else if constexpr (EPI == EFF1) {
          const int e = ebase + blockIdx.z;
          const float t = v + c0[(long)e * 4096 + col];
          const float rl = t > 0.f ? t : 0.f;
          const float pw = aux[(long)row * 8 + e];  // router prob folded in
          o0[(long)row * ldc + zc + col] = f2b(rl * pw);
        } else {  // EFF2 (accumulate) / EFF2I (init)
          const long idx = (long)row * 1024 + col;
          if constexpr (EPI == EFF2I)
            fout[idx] = v;
          else
            fout[idx] = fout[idx] + v;
        }
      }
  }
}

// ---------------------------------------------------------------- attention
// Swapped-operand flash attn: grid (S/64, B*H), 4 waves, 16 q-rows per wave,
// one q per lane (q = q0 + (lane&15)). QK^T swapped -> S^T (t in regs),
// PV swapped -> O^T. No LDS; P^T fragment built via 16 parallel shuffles.
__global__ __launch_bounds__(256) void attn_fwd(const u16* __restrict__ Qb,
                                                const u16* __restrict__ Kb,
                                                const u16* __restrict__ Vt,
                                                u16* __restrict__ Cat) {
  const int tid = threadIdx.x;
  const int w = tid >> 6, l = tid & 63;
  const int lr = l & 15, lh = l >> 4;
  const int bh = blockIdx.y;
  const int q0 = blockIdx.x * 64 + w * 16;
  const u16* Qp = Qb + (long)bh * 65536;
  const u16* Kp = Kb + (long)bh * 65536;
  const u16* Vp = Vt + (long)bh * 65536;  // [64 d][1024 t]
  const bf16x8 qf0 = *(const bf16x8*)&Qp[(q0 + lr) * 64 + lh * 8];
  const bf16x8 qf1 = *(const bf16x8*)&Qp[(q0 + lr) * 64 + 32 + lh * 8];
  const int q = q0 + lr;
  f32x4 o[4] = {};                 // O^T: d = dt*16 + lh*4 + r, this lane's q
  float m = -1e30f, ssum = 0.f;    // per-q running max / lane-partial sum
  const int hi = lh >> 1;
  const int s0 = ((lh & 1) * 2) * 16 + lr;
  const int s1 = ((lh & 1) * 2 + 1) * 16 + lr;
  const int nkt = q0 / 32 + 1;
  for (int kt = 0; kt < nkt; kt++) {
    const int t0 = kt * 32;
    f32x4 sc[2];  // S^T: t = t0 + ts*16 + lh*4 + r, col q
#pragma unroll
    for (int ts = 0; ts < 2; ts++) {
      const bf16x8 kf0 = *(const bf16x8*)&Kp[(t0 + ts * 16 + lr) * 64 + lh * 8];
      const bf16x8 kf1 =
          *(const bf16x8*)&Kp[(t0 + ts * 16 + lr) * 64 + 32 + lh * 8];
      f32x4 c = {};
      c = __builtin_amdgcn_mfma_f32_16x16x32_bf16(kf0, qf0, c, 0, 0, 0);
      c = __builtin_amdgcn_mfma_f32_16x16x32_bf16(kf1, qf1, c, 0, 0, 0);
      sc[ts] = c;
    }
#pragma unroll
    for (int ts = 0; ts < 2; ts++)
#pragma unroll
      for (int r = 0; r < 4; r++)
        if (t0 + ts * 16 + lh * 4 + r > q) sc[ts][r] = -1e30f;  // causal
    float mt = fmaxf(fmaxf(fmaxf(sc[0][0], sc[0][1]), fmaxf(sc[0][2], sc[0][3])),
                     fmaxf(fmaxf(sc[1][0], sc[1][1]), fmaxf(sc[1][2], sc[1][3])));
    mt = fmaxf(mt, __shfl_xor(mt, 16));
    mt = fmaxf(mt, __shfl_xor(mt, 32));
    const float mnew = fmaxf(m, mt);
    const float scl = __expf(m - mnew);
    m = mnew;
    float p0[4], p1[4], ps = 0.f;
#pragma unroll
    for (int r = 0; r < 4; r++) {
      p0[r] = __expf(sc[0][r] - mnew);
      p1[r] = __expf(sc[1][r] - mnew);
      ps += p0[r] + p1[r];
    }
    ssum = ssum * scl + ps;  // lane-partial; reduced once after the loop
    u16 pb[8];
#pragma unroll
    for (int r = 0; r < 4; r++) {
      const float a0 = __shfl(p0[r], s0), b0 = __shfl(p1[r], s0);
      const float a1 = __shfl(p0[r], s1), b1 = __shfl(p1[r], s1);
      pb[r] = f2b(hi ? b0 : a0);
      pb[r + 4] = f2b(hi ? b1 : a1);
    }
#pragma unroll
    for (int dt = 0; dt < 4; dt++)
#pragma unroll
      for (int r = 0; r < 4; r++) o[dt][r] *= scl;
    const bf16x8 pf = *(const bf16x8*)pb;
    __builtin_amdgcn_s_setprio(1);
#pragma unroll
    for (int dt = 0; dt < 4; dt++) {
      const bf16x8 vf =
          *(const bf16x8*)&Vp[(dt * 16 + lr) * 1024 + t0 + lh * 8];
      o[dt] = __builtin_amdgcn_mfma_f32_16x16x32_bf16(vf, pf, o[dt], 0, 0, 0);
    }
    __builtin_amdgcn_s_setprio(0);
  }
  ssum += __shfl_xor(ssum, 16);
  ssum += __shfl_xor(ssum, 32);
  const float inv = 1.f / ssum;
  const int b = bh >> 4, h = bh & 15;
#pragma unroll
  for (int dt = 0; dt < 4; dt++) {
    ushort4 st;
    st.x = f2b(o[dt][0] * inv);
    st.y = f2b(o[dt][1] * inv);
    st.z = f2b(o[dt][2] * inv);
    st.w = f2b(o[dt][3] * inv);
    *(ushort4*)&Cat[((long)(b * 1024 + q)) * 1024 + h * 64 + dt * 16 + lh * 4] =
        st;
  }
}

// ---------------------------------------------------------------- LN kernels
DEV float wred(float v) {
#pragma unroll
  for (int d = 1; d < 64; d <<= 1) v += __shfl_xor(v, d);
  return v;
}

__global__ __launch_bounds__(256) void ln1_router(
    const float* __restrict__ in, const float* __restrict__ g,
    const float* __restrict__ bb, const float* __restrict__ wr,
    const float* __restrict__ br, u16* __restrict__ h,
    float* __restrict__ probs) {
  __shared__ float rs[4], rs2[4], rp[4][8];
  const int row = blockIdx.x, t = threadIdx.x;
  const int w = t >> 6, l = t & 63;
  const float4 v = *(const float4*)&in[(long)row * 1024 + t * 4];
  float s = v.x + v.y + v.z + v.w;
  float s2 = v.x * v.x + v.y * v.y + v.z * v.z + v.w * v.w;
  s = wred(s);
  s2 = wred(s2);
  if (l == 0) { rs[w] = s; rs2[w] = s2; }
  __syncthreads();
  const float S = rs[0] + rs[1] + rs[2] + rs[3];
  const float S2 = rs2[0] + rs2[1] + rs2[2] + rs2[3];
  const float mean = S * (1.f / 1024.f);
  const float var = S2 * (1.f / 1024.f) - mean * mean;
  const float rr = rsqrtf(var + 1e-5f);
  const float4 gv = *(const float4*)&g[t * 4];
  const float4 bv = *(const float4*)&bb[t * 4];
  float hv[4];
  hv[0] = (v.x - mean) * rr * gv.x + bv.x;
  hv[1] = (v.y - mean) * rr * gv.y + bv.y;
  hv[2] = (v.z - mean) * rr * gv.z + bv.z;
  hv[3] = (v.w - mean) * rr * gv.w + bv.w;
  ushort4 hb;
  hb.x = f2b(hv[0]); hb.y = f2b(hv[1]); hb.z = f2b(hv[2]); hb.w = f2b(hv[3]);
  *(ushort4*)&h[(long)row * 1024 + t * 4] = hb;
  float pr[8] = {};
  const float* wrp = wr + t * 4 * 8;
#pragma unroll
  for (int e = 0; e < 4; e++)
#pragma unroll
    for (int j = 0; j < 8; j++) pr[j] += hv[e] * wrp[e * 8 + j];
#pragma unroll
  for (int j = 0; j < 8; j++) pr[j] = wred(pr[j]);
  if (l == 0)
#pragma unroll
    for (int j = 0; j < 8; j++) rp[w][j] = pr[j];
  __syncthreads();
  if (t == 0) {
    float lg[8], mx = -1e30f;
#pragma unroll
    for (int j = 0; j < 8; j++) {
      lg[j] = rp[0][j] + rp[1][j] + rp[2][j] + rp[3][j] + br[j];
      mx = fmaxf(mx, lg[j]);
    }
    float sm = 0.f;
#pragma unroll
    for (int j = 0; j < 8; j++) {
      lg[j] = __expf(lg[j] - mx);
      sm += lg[j];
    }
    const float inv = 1.f / sm;
#pragma unroll
    for (int j = 0; j < 8; j++) probs[row * 8 + j] = lg[j] * inv;
  }
}

// out = LN( sum_z moe_z + x + sum_n probs[n]*b2[n] )
__global__ __launch_bounds__(256) void ln2_kernel(
    const float* __restrict__ moe, const float* __restrict__ xres,
    const float* __restrict__ probs, const float* __restrict__ b2,
    const float* __restrict__ g, const float* __restrict__ bb,
    float* __restrict__ out, int np) {
  __shared__ float rs[4], rs2[4];
  const int row = blockIdx.x, t = threadIdx.x;
  const int w = t >> 6, l = t & 63;
  const long base = (long)row * 1024 + t * 4;
  float4 v = *(const float4*)&xres[base];
  for (int z = 0; z < np; z++) {
    const float4 a = *(const float4*)&moe[(long)z * 4194304 + base];
    v.x += a.x; v.y += a.y; v.z += a.z; v.w += a.w;
  }
#pragma unroll
  for (int n = 0; n < 8; n++) {
    const float pw = probs[(long)row * 8 + n];
    const float4 bv4 = *(const float4*)&b2[n * 1024 + t * 4];
    v.x += pw * bv4.x; v.y += pw * bv4.y;
    v.z += pw * bv4.z; v.w += pw * bv4.w;
  }
  float s = v.x + v.y + v.z + v.w;
  float s2 = v.x * v.x + v.y * v.y + v.z * v.z + v.w * v.w;
  s = wred(s);
  s2 = wred(s2);
  if (l == 0) { rs[w] = s; rs2[w] = s2; }
  __syncthreads();
  const float S = rs[0] + rs[1] + rs[2] + rs[3];
  const float S2 = rs2[0] + rs2[1] + rs2[2] + rs2[3];
  const float mean = S * (1.f / 1024.f);
  const float var = S2 * (1.f / 1024.f) - mean * mean;
  const float rr = rsqrtf(var + 1e-5f);
  const float4 gv = *(const float4*)&g[t * 4];
  const float4 bv = *(const float4*)&bb[t * 4];
  float4 oo;
  oo.x = (v.x - mean) * rr * gv.x + bv.x;
  oo.y = (v.y - mean) * rr * gv.y + bv.y;
  oo.z = (v.z - mean) * rr * gv.z + bv.z;
  oo.w = (v.w - mean) * rr * gv.w + bv.w;
  *(float4*)&out[base] = oo;
}

// ---------------------------------------------------------------- launch
extern "C" void kernel_launch(void* const* d_in, const int* in_sizes, int n_in,
                              void* d_out, int out_size, void* d_ws,
                              size_t ws_size, hipStream_t stream) {
  const float* x = (const float*)d_in[0];
  const float* wq = (const float*)d_in[1];
  const float* bq = (const float*)d_in[2];
  const float* wk = (const float*)d_in[3];
  const float* bk = (const float*)d_in[4];
  const float* wv = (const float*)d_in[5];
  const float* bv = (const float*)d_in[6];
  const float* wp = (const float*)d_in[7];
  const float* bp = (const float*)d_in[8];
  const float* g1 = (const float*)d_in[9];
  const float* be1 = (const float*)d_in[10];
  const float* g2 = (const float*)d_in[11];
  const float* be2 = (const float*)d_in[12];
  const float* wr = (const float*)d_in[13];
  const float* br = (const float*)d_in[14];
  const float* w1 = (const float*)d_in[15];
  const float* b1 = (const float*)d_in[16];
  const float* w2 = (const float*)d_in[17];
  const float* b2 = (const float*)d_in[18];
  float* out = (float*)d_out;

  char* p = (char*)d_ws;
  auto alloc = [&](size_t bytes) {
    char* r = p;
    p += (bytes + 255) & ~(size_t)255;
    return r;
  };
  // Layout (seq path footprint == proven 232 MB; fast path reuses dead
  // regions for moe slices 2,3 and for the 256 MB all-expert mid).
  u16* w1t = (u16*)alloc(67108864);    // [8][4096 f][1024 e]  B^T per expert
  u16* w2t2 = (u16*)alloc(67108864);   // [1024 e][8*4096]  (k = n*4096+f)
  u16* hb = (u16*)alloc(8388608);      // LN1 out bf16 [4096][1024]
  float* probs = (float*)alloc(131072);
  float* moe = (float*)alloc(33554432);   // fp32 partial slices 0,1
  float* resid1 = (float*)alloc(16777216);  // == moe slice 2 (fast path)
  u16* xb = (u16*)alloc(8388608);           // == moe slice 3 (fast path)
  u16* wqkvt = (u16*)alloc(6291456);
  u16* wpt = (u16*)alloc(2097152);
  u16* qb = (u16*)alloc(8388608);      // fast-path mid starts here (256 MB)
  u16* kb = (u16*)alloc(8388608);
  u16* vt = (u16*)alloc(8388608);
  u16* cat = (u16*)alloc(8388608);
  const size_t need_fast = (size_t)((char*)qb - (char*)d_ws) + (size_t)268435456;
  const bool fast = ws_size >= need_fast;

  const dim3 tb(32, 8);
  cvt_bf16<<<4096, 256, 0, stream>>>(x, xb);
  tpose_bf16<<<dim3(2, 32, 16), tb, 0, stream>>>(wq, wqkvt, 1024, 64, 65536, 65536, 1024);
  tpose_bf16<<<dim3(2, 32, 16), tb, 0, stream>>>(wk, wqkvt + 1048576, 1024, 64, 65536, 65536, 1024);
  tpose_bf16<<<dim3(2, 32, 16), tb, 0, stream>>>(wv, wqkvt + 2097152, 1024, 64, 65536, 65536, 1024);
  tpose_bf16<<<dim3(32, 32, 1), tb, 0, stream>>>(wp, wpt, 1024, 1024, 0, 0, 1024);
  tpose_bf16<<<dim3(128, 32, 8), tb, 0, stream>>>(w1, w1t, 1024, 4096, 4194304, 4194304, 1024);
  tpose_bf16<<<dim3(32, 128, 8), tb, 0, stream>>>(w2, w2t2, 4096, 1024, 4194304, 4096, 32768);

  gemm_bt<EQKV><<<dim3(24, 32), 256, 0, stream>>>(
      xb, wqkvt, 1024, 1024, 1024, bq, bk, bv, nullptr, nullptr, qb, kb, vt,
      0, 0);
  attn_fwd<<<dim3(16, 64), 256, 0, stream>>>(qb, kb, vt, cat);
  gemm_bt<EPROJ><<<dim3(8, 32), 256, 0, stream>>>(
      cat, wpt, 1024, 1024, 1024, bp, nullptr, nullptr, x, resid1, nullptr,
      nullptr, nullptr, 0, 0);
  ln1_router<<<4096, 256, 0, stream>>>(resid1, g1, be1, wr, br, hb, probs);

  if (fast) {
    u16* mid = qb;  // [4096][8*4096] bf16, aliases qb..cat + fresh tail
    gemm_bt<EFF1><<<dim3(32, 32, 8), 256, 0, stream>>>(
        hb, w1t, 1024, 1024, 1024, b1, nullptr, nullptr, probs, nullptr, mid,
        nullptr, nullptr, 0, 32768);
    gemm_bt<EFF2I><<<dim3(8, 32, 4), 256, 0, stream>>>(
        mid, w2t2, 8192, 32768, 32768, nullptr, nullptr, nullptr, nullptr,
        moe, nullptr, nullptr, nullptr, 0, 0);
    ln2_kernel<<<4096, 256, 0, stream>>>(moe, x, probs, b2, g2, be2, out, 4);
  } else {
    u16* mid = qb;  // [4096][4096] bf16 per expert, reused (32 MB)
    for (int n = 0; n < 8; n++) {
      gemm_bt<EFF1><<<dim3(32, 32, 1), 256, 0, stream>>>(
          hb, w1t + (long)n * 4194304, 1024, 1024, 1024, b1, nullptr, nullptr,
          probs, nullptr, mid, nullptr, nullptr, n, 4096);
      if (n == 0)
        gemm_bt<EFF2I><<<dim3(8, 32, 2), 256, 0, stream>>>(
            mid, w2t2 + (long)n * 4096, 2048, 4096, 32768, nullptr, nullptr,
            nullptr, nullptr, moe, nullptr, nullptr, nullptr, 0, 0);
      else
        gemm_bt<EFF2><<<dim3(8, 32, 2), 256, 0, stream>>>(
            mid, w2t2 + (long)n * 4096, 2048, 4096, 32768, nullptr, nullptr,
            nullptr, nullptr, moe, nullptr, nullptr, nullptr, 0, 0);
    }
    ln2_kernel<<<4096, 256, 0, stream>>>(moe, x, probs, b2, g2, be2, out, 2);
  }
}

// Round 9
// 1394.439 us; speedup vs baseline: 1.0773x; 1.0773x over previous
//
#include <hip/hip_runtime.h>
#include <hip/hip_bf16.h>

typedef unsigned short u16;
typedef unsigned int u32;
typedef __attribute__((ext_vector_type(8))) short bf16x8;
typedef __attribute__((ext_vector_type(4))) float f32x4;

#define DEV static __device__ __forceinline__

// fp32 -> bf16, round-to-nearest-even
DEV u16 f2b(float f) {
  union { float f; u32 u; } v; v.f = f;
  return (u16)((v.u + 0x7fffu + ((v.u >> 16) & 1u)) >> 16);
}

// async global->LDS, 16B per lane. LDS dest linear in lane order.
DEV void gload16(const void* g, void* l) {
  __builtin_amdgcn_global_load_lds(
      (const __attribute__((address_space(1))) u32*)g,
      (__attribute__((address_space(3))) u32*)l, 16, 0, 0);
}

// ---------------------------------------------------------------- converts
__global__ __launch_bounds__(256) void cvt_bf16(const float* __restrict__ s,
                                                u16* __restrict__ d) {
  const long i = ((long)blockIdx.x * 256 + threadIdx.x) * 4;
  const float4 v = *(const float4*)&s[i];
  ushort4 o;
  o.x = f2b(v.x); o.y = f2b(v.y); o.z = f2b(v.z); o.w = f2b(v.w);
  *(ushort4*)&d[i] = o;
}

// src [bz][R][C] fp32 -> dst: elem [c][r] at dst + bz*dStride + c*ldd + r
__global__ __launch_bounds__(256) void tpose_bf16(const float* __restrict__ src,
                                                  u16* __restrict__ dst, int R,
                                                  int C, long sStride,
                                                  long dStride, long ldd) {
  __shared__ float tl[32][33];
  const float* s = src + (long)blockIdx.z * sStride;
  u16* d = dst + (long)blockIdx.z * dStride;
  const int c0 = blockIdx.x * 32, r0 = blockIdx.y * 32;
  const int tx = threadIdx.x, ty = threadIdx.y;  // (32,8)
  const int tid = ty * 32 + tx;
#pragma unroll
  for (int k = 0; k < 4; k++)
    tl[ty + k * 8][tx] = s[(long)(r0 + ty + k * 8) * C + c0 + tx];
  __syncthreads();
  const int oc = tid >> 3, orb = (tid & 7) * 4;
  ushort4 o;
  o.x = f2b(tl[orb + 0][oc]);
  o.y = f2b(tl[orb + 1][oc]);
  o.z = f2b(tl[orb + 2][oc]);
  o.w = f2b(tl[orb + 3][oc]);
  *(ushort4*)&d[(long)(c0 + oc) * ldd + r0 + orb] = o;
}

// ---------------------------------------------------------------- GEMM
// C[row][col] = sum_k A[row][k] * Bt[col][k]   (A row-major, B^T row-major)
// 128x128 tile, BK=32, 4 waves (2x2), 4x4 mfma_f32_16x16x32_bf16 per K-step.
// Minimum 2-phase double buffer (T3 recipe): stage tile t+1 into buf^1, then
// compute tile t from buf, ONE __syncthreads per step (its vmcnt(0) drain
// lands AFTER compute, so stage latency hides under the MFMAs). 32 KB LDS ->
// 4 blocks/CU. T2 XOR swizzle (col ^= (row&3)<<3 in u16) applied on the
// GLOBAL source col for staging and on the ds_read col (rule 21 both-sides).
// T1 bijective XCD chunk-swizzle on (bx,by): same-A blocks share one L2.
enum { EQKV, EPROJ, EFF1, EFF2, EFF2I };

template <int EPI>
__global__ __launch_bounds__(256, 4) void gemm_bt(
    const u16* __restrict__ A, const u16* __restrict__ Bt, int K, long lda,
    long ldb, const float* __restrict__ c0, const float* __restrict__ c1,
    const float* __restrict__ c2, const float* __restrict__ aux,
    float* __restrict__ fout, u16* __restrict__ o0, u16* __restrict__ o1,
    u16* __restrict__ o2, int ebase, long ldc) {
  __shared__ u16 As[8192], Bs[8192];  // 2 bufs x (128 rows x 32 k) each
  long zc = 0;
  if constexpr (EPI == EFF2 || EPI == EFF2I) {  // K-split over grid.z
    const long z = blockIdx.z;
    A += z * (long)K;
    Bt += z * (long)K;
    fout += z * 4194304;  // per-z fp32 partial [4096][1024]
  }
  if constexpr (EPI == EFF1) {  // expert-batch over grid.z
    Bt += (long)blockIdx.z * 4194304;
    zc = (long)blockIdx.z * 4096;
  }
  // T1: XCD chunk swizzle (bijective; all grids have gx*gy % 8 == 0).
  // HW round-robins dispatch-linear id across 8 XCDs; remap so XCD k
  // computes a CONTIGUOUS tile chunk -> same-A neighbors share one L2.
  const int gx = gridDim.x, cpx = (gx * gridDim.y) >> 3;
  const int lin = blockIdx.x + gx * blockIdx.y;
  const int swz = (lin & 7) * cpx + (lin >> 3);
  const int m0 = (swz / gx) * 128, n0 = (swz % gx) * 128;
  const int tid = threadIdx.x;
  const int w = tid >> 6, l = tid & 63;
  const int wm = (w >> 1) * 64, wn = (w & 1) * 64;
  const int lr = l & 15, lh = l >> 4;
  f32x4 acc[4][4] = {};
  // staging: lane -> row tid>>2 (+64 for 2nd gload), semantic col (tid&3)*8,
  // pre-swizzled source col = c ^ ((row&3)<<3)  (row&3 == (tid>>2)&3)
  const int scol = ((tid & 3) * 8) ^ (((tid >> 2) & 3) << 3);
  const u16* Ag = A + (long)(m0 + (tid >> 2)) * lda + scol;
  const u16* Bg = Bt + (long)(n0 + (tid >> 2)) * ldb + scol;
  const long rsA = 64 * lda, rsB = 64 * ldb;
  u16* asd = As + tid * 8;
  u16* bsd = Bs + tid * 8;
  const int nt = K >> 5;
  // prologue: stage tile 0 into buf0
  gload16(Ag, asd);  gload16(Ag + rsA, asd + 2048);
  gload16(Bg, bsd);  gload16(Bg + rsB, bsd + 2048);
  __syncthreads();
  int cur = 0;
  // ds_read col: base lh*8, swizzled by (row&3)<<3 with row&3 == lr&3
  const int cswz = (lh * 8) ^ ((lr & 3) << 3);
  for (int t = 0; t < nt; ++t) {
    if (t + 1 < nt) {  // stage tile t+1 into the other buffer
      const int ks = (t + 1) * 32;
      const int od = (cur ^ 1) * 4096;
      gload16(Ag + ks, asd + od);
      gload16(Ag + rsA + ks, asd + od + 2048);
      gload16(Bg + ks, bsd + od);
      gload16(Bg + rsB + ks, bsd + od + 2048);
    }
    const int ob = cur * 4096;
    bf16x8 af[4], bfr[4];
#pragma unroll
    for (int i = 0; i < 4; i++)
      af[i] = *(const bf16x8*)&As[ob + (wm + i * 16 + lr) * 32 + cswz];
#pragma unroll
    for (int j = 0; j < 4; j++)
      bfr[j] = *(const bf16x8*)&Bs[ob + (wn + j * 16 + lr) * 32 + cswz];
#pragma unroll
    for (int i = 0; i < 4; i++)
#pragma unroll
      for (int j = 0; j < 4; j++)
        acc[i][j] = __builtin_amdgcn_mfma_f32_16x16x32_bf16(af[i], bfr[j],
                                                            acc[i][j], 0, 0, 0);
    __syncthreads();  // drains vmcnt/lgkmcnt AFTER compute: stage overlapped
    cur ^= 1;
  }
  // epilogue: elem (i,j,r) -> row = m0+wm+i*16+lh*4+r, col = n0+wn+j*16+lr
#pragma unroll
  for (int j = 0; j < 4; j++) {
    const int col = n0 + wn + j * 16 + lr;
#pragma unroll
    for (int i = 0; i < 4; i++)
#pragma unroll
      for (int r = 0; r < 4; r++) {
        const int row = m0 + wm + i * 16 + lh * 4 + r;
        float v = acc[i][j][r];
        if constexpr (EPI == EQKV) {
          const int which = col >> 10, hd = col & 1023;
          const float vb =
              v + ((which == 0) ? c0 : (which == 1) ? c1 : c2)[hd];
          const int b = row >> 10, s = row & 1023;
          const int h = hd >> 6, d = hd & 63;
          const long bh = b * 16 + h;
          if (which == 0)
            o0[(bh * 1024 + s) * 64 + d] = f2b(vb * 0.125f);  // q pre-scaled
          else if (which == 1)
            o1[(bh * 1024 + s) * 64 + d] = f2b(vb);           // k
          else
            o2[bh * 65536 + (long)d * 1024 + s] = f2b(vb);    // v transposed
        } else if constexpr (EPI == EPROJ) {
          const long idx = (long)row * 1024 + col;
          fout[idx] = v + c0[col] + aux[idx];  // + bp + x residual
        } else if constexpr (EPI == EFF1) {
          const int e = ebase + blockIdx.z;
          const float t = v + c0[(long)e * 4096 + col];
          const float rl = t > 0.f ? t : 0.f;
          const float pw = aux[(long)row * 8 + e];  // router prob folded in
          o0[(long)row * ldc + zc + col] = f2b(rl * pw);
        } else {  // EFF2 (accumulate) / EFF2I (init)
          const long idx = (long)row * 1024 + col;
          if constexpr (EPI == EFF2I)
            fout[idx] = v;
          else
            fout[idx] = fout[idx] + v;
        }
      }
  }
}

// ---------------------------------------------------------------- attention
// Swapped-operand flash attn: grid (S/64, B*H), 4 waves, 16 q-rows per wave,
// one q per lane (q = q0 + (lane&15)). QK^T swapped -> S^T (t in regs),
// PV swapped -> O^T. No LDS; P^T fragment built via 16 parallel shuffles.
__global__ __launch_bounds__(256) void attn_fwd(const u16* __restrict__ Qb,
                                                const u16* __restrict__ Kb,
                                                const u16* __restrict__ Vt,
                                                u16* __restrict__ Cat) {
  const int tid = threadIdx.x;
  const int w = tid >> 6, l = tid & 63;
  const int lr = l & 15, lh = l >> 4;
  const int bh = blockIdx.y;
  const int q0 = blockIdx.x * 64 + w * 16;
  const u16* Qp = Qb + (long)bh * 65536;
  const u16* Kp = Kb + (long)bh * 65536;
  const u16* Vp = Vt + (long)bh * 65536;  // [64 d][1024 t]
  const bf16x8 qf0 = *(const bf16x8*)&Qp[(q0 + lr) * 64 + lh * 8];
  const bf16x8 qf1 = *(const bf16x8*)&Qp[(q0 + lr) * 64 + 32 + lh * 8];
  const int q = q0 + lr;
  f32x4 o[4] = {};                 // O^T: d = dt*16 + lh*4 + r, this lane's q
  float m = -1e30f, ssum = 0.f;    // per-q running max / lane-partial sum
  const int hi = lh >> 1;
  const int s0 = ((lh & 1) * 2) * 16 + lr;
  const int s1 = ((lh & 1) * 2 + 1) * 16 + lr;
  const int nkt = q0 / 32 + 1;
  for (int kt = 0; kt < nkt; kt++) {
    const int t0 = kt * 32;
    f32x4 sc[2];  // S^T: t = t0 + ts*16 + lh*4 + r, col q
#pragma unroll
    for (int ts = 0; ts < 2; ts++) {
      const bf16x8 kf0 = *(const bf16x8*)&Kp[(t0 + ts * 16 + lr) * 64 + lh * 8];
      const bf16x8 kf1 =
          *(const bf16x8*)&Kp[(t0 + ts * 16 + lr) * 64 + 32 + lh * 8];
      f32x4 c = {};
      c = __builtin_amdgcn_mfma_f32_16x16x32_bf16(kf0, qf0, c, 0, 0, 0);
      c = __builtin_amdgcn_mfma_f32_16x16x32_bf16(kf1, qf1, c, 0, 0, 0);
      sc[ts] = c;
    }
#pragma unroll
    for (int ts = 0; ts < 2; ts++)
#pragma unroll
      for (int r = 0; r < 4; r++)
        if (t0 + ts * 16 + lh * 4 + r > q) sc[ts][r] = -1e30f;  // causal
    float mt = fmaxf(fmaxf(fmaxf(sc[0][0], sc[0][1]), fmaxf(sc[0][2], sc[0][3])),
                     fmaxf(fmaxf(sc[1][0], sc[1][1]), fmaxf(sc[1][2], sc[1][3])));
    mt = fmaxf(mt, __shfl_xor(mt, 16));
    mt = fmaxf(mt, __shfl_xor(mt, 32));
    const float mnew = fmaxf(m, mt);
    const float scl = __expf(m - mnew);
    m = mnew;
    float p0[4], p1[4], ps = 0.f;
#pragma unroll
    for (int r = 0; r < 4; r++) {
      p0[r] = __expf(sc[0][r] - mnew);
      p1[r] = __expf(sc[1][r] - mnew);
      ps += p0[r] + p1[r];
    }
    ssum = ssum * scl + ps;  // lane-partial; reduced once after the loop
    u16 pb[8];
#pragma unroll
    for (int r = 0; r < 4; r++) {
      const float a0 = __shfl(p0[r], s0), b0 = __shfl(p1[r], s0);
      const float a1 = __shfl(p0[r], s1), b1 = __shfl(p1[r], s1);
      pb[r] = f2b(hi ? b0 : a0);
      pb[r + 4] = f2b(hi ? b1 : a1);
    }
#pragma unroll
    for (int dt = 0; dt < 4; dt++)
#pragma unroll
      for (int r = 0; r < 4; r++) o[dt][r] *= scl;
    const bf16x8 pf = *(const bf16x8*)pb;
    __builtin_amdgcn_s_setprio(1);
#pragma unroll
    for (int dt = 0; dt < 4; dt++) {
      const bf16x8 vf =
          *(const bf16x8*)&Vp[(dt * 16 + lr) * 1024 + t0 + lh * 8];
      o[dt] = __builtin_amdgcn_mfma_f32_16x16x32_bf16(vf, pf, o[dt], 0, 0, 0);
    }
    __builtin_amdgcn_s_setprio(0);
  }
  ssum += __shfl_xor(ssum, 16);
  ssum += __shfl_xor(ssum, 32);
  const float inv = 1.f / ssum;
  const int b = bh >> 4, h = bh & 15;
#pragma unroll
  for (int dt = 0; dt < 4; dt++) {
    ushort4 st;
    st.x = f2b(o[dt][0] * inv);
    st.y = f2b(o[dt][1] * inv);
    st.z = f2b(o[dt][2] * inv);
    st.w = f2b(o[dt][3] * inv);
    *(ushort4*)&Cat[((long)(b * 1024 + q)) * 1024 + h * 64 + dt * 16 + lh * 4] =
        st;
  }
}

// ---------------------------------------------------------------- LN kernels
DEV float wred(float v) {
#pragma unroll
  for (int d = 1; d < 64; d <<= 1) v += __shfl_xor(v, d);
  return v;
}

__global__ __launch_bounds__(256) void ln1_router(
    const float* __restrict__ in, const float* __restrict__ g,
    const float* __restrict__ bb, const float* __restrict__ wr,
    const float* __restrict__ br, u16* __restrict__ h,
    float* __restrict__ probs) {
  __shared__ float rs[4], rs2[4], rp[4][8];
  const int row = blockIdx.x, t = threadIdx.x;
  const int w = t >> 6, l = t & 63;
  const float4 v = *(const float4*)&in[(long)row * 1024 + t * 4];
  float s = v.x + v.y + v.z + v.w;
  float s2 = v.x * v.x + v.y * v.y + v.z * v.z + v.w * v.w;
  s = wred(s);
  s2 = wred(s2);
  if (l == 0) { rs[w] = s; rs2[w] = s2; }
  __syncthreads();
  const float S = rs[0] + rs[1] + rs[2] + rs[3];
  const float S2 = rs2[0] + rs2[1] + rs2[2] + rs2[3];
  const float mean = S * (1.f / 1024.f);
  const float var = S2 * (1.f / 1024.f) - mean * mean;
  const float rr = rsqrtf(var + 1e-5f);
  const float4 gv = *(const float4*)&g[t * 4];
  const float4 bv = *(const float4*)&bb[t * 4];
  float hv[4];
  hv[0] = (v.x - mean) * rr * gv.x + bv.x;
  hv[1] = (v.y - mean) * rr * gv.y + bv.y;
  hv[2] = (v.z - mean) * rr * gv.z + bv.z;
  hv[3] = (v.w - mean) * rr * gv.w + bv.w;
  ushort4 hb;
  hb.x = f2b(hv[0]); hb.y = f2b(hv[1]); hb.z = f2b(hv[2]); hb.w = f2b(hv[3]);
  *(ushort4*)&h[(long)row * 1024 + t * 4] = hb;
  float pr[8] = {};
  const float* wrp = wr + t * 4 * 8;
#pragma unroll
  for (int e = 0; e < 4; e++)
#pragma unroll
    for (int j = 0; j < 8; j++) pr[j] += hv[e] * wrp[e * 8 + j];
#pragma unroll
  for (int j = 0; j < 8; j++) pr[j] = wred(pr[j]);
  if (l == 0)
#pragma unroll
    for (int j = 0; j < 8; j++) rp[w][j] = pr[j];
  __syncthreads();
  if (t == 0) {
    float lg[8], mx = -1e30f;
#pragma unroll
    for (int j = 0; j < 8; j++) {
      lg[j] = rp[0][j] + rp[1][j] + rp[2][j] + rp[3][j] + br[j];
      mx = fmaxf(mx, lg[j]);
    }
    float sm = 0.f;
#pragma unroll
    for (int j = 0; j < 8; j++) {
      lg[j] = __expf(lg[j] - mx);
      sm += lg[j];
    }
    const float inv = 1.f / sm;
#pragma unroll
    for (int j = 0; j < 8; j++) probs[row * 8 + j] = lg[j] * inv;
  }
}

// out = LN( sum_z moe_z + x + sum_n probs[n]*b2[n] )
__global__ __launch_bounds__(256) void ln2_kernel(
    const float* __restrict__ moe, const float* __restrict__ xres,
    const float* __restrict__ probs, const float* __restrict__ b2,
    const float* __restrict__ g, const float* __restrict__ bb,
    float* __restrict__ out, int np) {
  __shared__ float rs[4], rs2[4];
  const int row = blockIdx.x, t = threadIdx.x;
  const int w = t >> 6, l = t & 63;
  const long base = (long)row * 1024 + t * 4;
  float4 v = *(const float4*)&xres[base];
  for (int z = 0; z < np; z++) {
    const float4 a = *(const float4*)&moe[(long)z * 4194304 + base];
    v.x += a.x; v.y += a.y; v.z += a.z; v.w += a.w;
  }
#pragma unroll
  for (int n = 0; n < 8; n++) {
    const float pw = probs[(long)row * 8 + n];
    const float4 bv4 = *(const float4*)&b2[n * 1024 + t * 4];
    v.x += pw * bv4.x; v.y += pw * bv4.y;
    v.z += pw * bv4.z; v.w += pw * bv4.w;
  }
  float s = v.x + v.y + v.z + v.w;
  float s2 = v.x * v.x + v.y * v.y + v.z * v.z + v.w * v.w;
  s = wred(s);
  s2 = wred(s2);
  if (l == 0) { rs[w] = s; rs2[w] = s2; }
  __syncthreads();
  const float S = rs[0] + rs[1] + rs[2] + rs[3];
  const float S2 = rs2[0] + rs2[1] + rs2[2] + rs2[3];
  const float mean = S * (1.f / 1024.f);
  const float var = S2 * (1.f / 1024.f) - mean * mean;
  const float rr = rsqrtf(var + 1e-5f);
  const float4 gv = *(const float4*)&g[t * 4];
  const float4 bv = *(const float4*)&bb[t * 4];
  float4 oo;
  oo.x = (v.x - mean) * rr * gv.x + bv.x;
  oo.y = (v.y - mean) * rr * gv.y + bv.y;
  oo.z = (v.z - mean) * rr * gv.z + bv.z;
  oo.w = (v.w - mean) * rr * gv.w + bv.w;
  *(float4*)&out[base] = oo;
}

// ---------------------------------------------------------------- launch
extern "C" void kernel_launch(void* const* d_in, const int* in_sizes, int n_in,
                              void* d_out, int out_size, void* d_ws,
                              size_t ws_size, hipStream_t stream) {
  const float* x = (const float*)d_in[0];
  const float* wq = (const float*)d_in[1];
  const float* bq = (const float*)d_in[2];
  const float* wk = (const float*)d_in[3];
  const float* bk = (const float*)d_in[4];
  const float* wv = (const float*)d_in[5];
  const float* bv = (const float*)d_in[6];
  const float* wp = (const float*)d_in[7];
  const float* bp = (const float*)d_in[8];
  const float* g1 = (const float*)d_in[9];
  const float* be1 = (const float*)d_in[10];
  const float* g2 = (const float*)d_in[11];
  const float* be2 = (const float*)d_in[12];
  const float* wr = (const float*)d_in[13];
  const float* br = (const float*)d_in[14];
  const float* w1 = (const float*)d_in[15];
  const float* b1 = (const float*)d_in[16];
  const float* w2 = (const float*)d_in[17];
  const float* b2 = (const float*)d_in[18];
  float* out = (float*)d_out;

  char* p = (char*)d_ws;
  auto alloc = [&](size_t bytes) {
    char* r = p;
    p += (bytes + 255) & ~(size_t)255;
    return r;
  };
  // Layout (seq path footprint == proven 232 MB; fast path reuses dead
  // regions for moe slices 2,3 and for the 256 MB all-expert mid).
  u16* w1t = (u16*)alloc(67108864);    // [8][4096 f][1024 e]  B^T per expert
  u16* w2t2 = (u16*)alloc(67108864);   // [1024 e][8*4096]  (k = n*4096+f)
  u16* hb = (u16*)alloc(8388608);      // LN1 out bf16 [4096][1024]
  float* probs = (float*)alloc(131072);
  float* moe = (float*)alloc(33554432);   // fp32 partial slices 0,1
  float* resid1 = (float*)alloc(16777216);  // == moe slice 2 (fast path)
  u16* xb = (u16*)alloc(8388608);           // == moe slice 3 (fast path)
  u16* wqkvt = (u16*)alloc(6291456);
  u16* wpt = (u16*)alloc(2097152);
  u16* qb = (u16*)alloc(8388608);      // fast-path mid starts here (256 MB)
  u16* kb = (u16*)alloc(8388608);
  u16* vt = (u16*)alloc(8388608);
  u16* cat = (u16*)alloc(8388608);
  const size_t need_fast = (size_t)((char*)qb - (char*)d_ws) + (size_t)268435456;
  const bool fast = ws_size >= need_fast;

  const dim3 tb(32, 8);
  cvt_bf16<<<4096, 256, 0, stream>>>(x, xb);
  tpose_bf16<<<dim3(2, 32, 16), tb, 0, stream>>>(wq, wqkvt, 1024, 64, 65536, 65536, 1024);
  tpose_bf16<<<dim3(2, 32, 16), tb, 0, stream>>>(wk, wqkvt + 1048576, 1024, 64, 65536, 65536, 1024);
  tpose_bf16<<<dim3(2, 32, 16), tb, 0, stream>>>(wv, wqkvt + 2097152, 1024, 64, 65536, 65536, 1024);
  tpose_bf16<<<dim3(32, 32, 1), tb, 0, stream>>>(wp, wpt, 1024, 1024, 0, 0, 1024);
  tpose_bf16<<<dim3(128, 32, 8), tb, 0, stream>>>(w1, w1t, 1024, 4096, 4194304, 4194304, 1024);
  tpose_bf16<<<dim3(32, 128, 8), tb, 0, stream>>>(w2, w2t2, 4096, 1024, 4194304, 4096, 32768);

  gemm_bt<EQKV><<<dim3(24, 32), 256, 0, stream>>>(
      xb, wqkvt, 1024, 1024, 1024, bq, bk, bv, nullptr, nullptr, qb, kb, vt,
      0, 0);
  attn_fwd<<<dim3(16, 64), 256, 0, stream>>>(qb, kb, vt, cat);
  gemm_bt<EPROJ><<<dim3(8, 32), 256, 0, stream>>>(
      cat, wpt, 1024, 1024, 1024, bp, nullptr, nullptr, x, resid1, nullptr,
      nullptr, nullptr, 0, 0);
  ln1_router<<<4096, 256, 0, stream>>>(resid1, g1, be1, wr, br, hb, probs);

  if (fast) {
    u16* mid = qb;  // [4096][8*4096] bf16, aliases qb..cat + fresh tail
    gemm_bt<EFF1><<<dim3(32, 32, 8), 256, 0, stream>>>(
        hb, w1t, 1024, 1024, 1024, b1, nullptr, nullptr, probs, nullptr, mid,
        nullptr, nullptr, 0, 32768);
    gemm_bt<EFF2I><<<dim3(8, 32, 4), 256, 0, stream>>>(
        mid, w2t2, 8192, 32768, 32768, nullptr, nullptr, nullptr, nullptr,
        moe, nullptr, nullptr, nullptr, 0, 0);
    ln2_kernel<<<4096, 256, 0, stream>>>(moe, x, probs, b2, g2, be2, out, 4);
  } else {
    u16* mid = qb;  // [4096][4096] bf16 per expert, reused (32 MB)
    for (int n = 0; n < 8; n++) {
      gemm_bt<EFF1><<<dim3(32, 32, 1), 256, 0, stream>>>(
          hb, w1t + (long)n * 4194304, 1024, 1024, 1024, b1, nullptr, nullptr,
          probs, nullptr, mid, nullptr, nullptr, n, 4096);
      if (n == 0)
        gemm_bt<EFF2I><<<dim3(8, 32, 2), 256, 0, stream>>>(
            mid, w2t2 + (long)n * 4096, 2048, 4096, 32768, nullptr, nullptr,
            nullptr, nullptr, moe, nullptr, nullptr, nullptr, 0, 0);
      else
        gemm_bt<EFF2><<<dim3(8, 32, 2), 256, 0, stream>>>(
            mid, w2t2 + (long)n * 4096, 2048, 4096, 32768, nullptr, nullptr,
            nullptr, nullptr, moe, nullptr, nullptr, nullptr, 0, 0);
    }
    ln2_kernel<<<4096, 256, 0, stream>>>(moe, x, probs, b2, g2, be2, out, 2);
  }
}